// Round 2
// 315.458 us; speedup vs baseline: 1.0182x; 1.0182x over previous
//
#include <hip/hip_runtime.h>

#define NFFT  2048
#define KF    1025
#define MROWS 2050
#define TT    513
#define HOPS  512
#define LSIG  262144
#define PADL  1024
#define XPADN 264192              // LSIG + 2*PADL
#define XDN   66048               // XPADN / 4 (deinterleaved plane length)
#define IMOFF (16 * MROWS * TT)
#define NBC   32

typedef __attribute__((ext_vector_type(8))) short bf16x8;
typedef __attribute__((ext_vector_type(4))) short bf16x4;
typedef __attribute__((ext_vector_type(4))) float f32x4;

__device__ __forceinline__ short f2bf(float f) {
    union { float f; unsigned u; } v; v.f = f;
    unsigned r = v.u + 0x7fffu + ((v.u >> 16) & 1u);
    return (short)(r >> 16);
}

typedef __attribute__((address_space(1))) void gas_void;
typedef __attribute__((address_space(3))) void las_void;

__device__ __forceinline__ void gload_lds16(const short* g, short* l) {
    __builtin_amdgcn_global_load_lds((gas_void*)(void*)const_cast<short*>(g),
                                     (las_void*)(void*)l, 16, 0, 0);
}

// ---- prep: reflect-padded x -> bf16 xpad[32][264192] AND deinterleaved xd[4][32][66048]
__global__ __launch_bounds__(256)
void prep_x(const float* __restrict__ x, short* __restrict__ xpad,
            short* __restrict__ xd) {
    const int bc = blockIdx.y;
    const int j4 = (blockIdx.x * 256 + threadIdx.x) * 4;   // 258*256*4 = 264192 exact
    const float* xb = x + (size_t)bc * LSIG;
    float4 v;
    if (j4 >= PADL && j4 + 4 <= PADL + LSIG) {
        v = *(const float4*)(xb + (j4 - PADL));
    } else {
        float t[4];
#pragma unroll
        for (int e = 0; e < 4; e++) {
            int s = j4 + e - PADL;
            if (s < 0) s = -s;
            if (s >= LSIG) s = 2 * LSIG - 2 - s;
            t[e] = xb[s];
        }
        v = make_float4(t[0], t[1], t[2], t[3]);
    }
    bf16x4 b = { f2bf(v.x), f2bf(v.y), f2bf(v.z), f2bf(v.w) };
    *(bf16x4*)(xpad + (size_t)bc * XPADN + j4) = b;
    const int j = j4 >> 2;                                 // n = 4j + r
#pragma unroll
    for (int r = 0; r < 4; r++)
        xd[((size_t)r * NBC + bc) * XDN + j] = b[r];
}

// ---- prep: twiddle-baked radix-4 basis.
// A'[r][row=2kap+reim][m] = (reim ? wi : wr)[kap][4m+r]  (pure gather, no trig)
// since tw_r(kap) * (windowed sub-DFT row) == windowed full-DFT row sampled at n=4m+r.
__global__ __launch_bounds__(256)
void prep_basis2(const float* __restrict__ wr, const float* __restrict__ wi,
                 short* __restrict__ A) {
    const int r   = blockIdx.y;
    const int row = blockIdx.x;               // 0..511, kap = row>>1
    const float* w = ((row & 1) ? wi : wr) + (size_t)(row >> 1) * NFFT + r;
    short* dst = A + ((size_t)r * 512 + row) * 512;
    for (int m = threadIdx.x; m < 512; m += 256)
        dst[m] = f2bf(w[4 * m]);
}

// ---- fused radix-4 GEMM + combine epilogue.
// Block: 128 basis rows (64 kaps) x 64 t; 4 waves (2x2), wave = 64 rows x 32 t.
// acc[r][i][j]: 4 r-planes kept separate (128 VGPR), butterfly at store time.
// blockIdx.z == 8 covers only t=512 (guarded stores; B rows clamped in-plane).
__global__ __launch_bounds__(256, 2)
void stft_gemm_f(const short* __restrict__ Ab, const short* __restrict__ xd,
                 float* __restrict__ out) {
    __shared__ short As[2][128 * 64];
    __shared__ short Bs[2][64 * 64];

    const int tid   = threadIdx.x;
    const int bcg   = blockIdx.x;
    const int mBase = blockIdx.y * 128;
    const int t0    = blockIdx.z * 64;

    const int lane = tid & 63;
    const int wid  = tid >> 6;
    const int wm   = (wid >> 1) * 64;
    const int wn   = (wid & 1) * 32;
    const int l16  = lane & 15;
    const int quad = lane >> 4;

    const int lrow = lane >> 3;
    const int csrc = (lane & 7) ^ lrow;
    const int rbA  = 32 * wid;
    const int rbB  = 16 * wid;

    // clamped B frame-rows (t=512 block reads rows >515 otherwise; garbage ok, OOB not)
    int br0 = t0 + rbB + lrow;       if (br0 > 515) br0 = 515;
    int br1 = t0 + rbB + 8 + lrow;   if (br1 > 515) br1 = 515;

    f32x4 acc[4][4][2];
#pragma unroll
    for (int r = 0; r < 4; r++)
#pragma unroll
        for (int i = 0; i < 4; i++)
#pragma unroll
            for (int j = 0; j < 2; j++)
                acc[r][i][j] = (f32x4){0.f, 0.f, 0.f, 0.f};

    const int r7 = l16 & 7;

#pragma unroll
    for (int rp = 0; rp < 2; rp++) {
        const short* Ap0 = Ab + ((size_t)(2 * rp) * 512 + mBase + rbA + lrow) * 512 + csrc * 8;
        const short* Ap1 = Ap0 + (size_t)512 * 512;
        const short* Bbase0 = xd + ((size_t)(2 * rp) * NBC + bcg) * XDN + csrc * 8;
        const short* Bbase1 = Bbase0 + (size_t)NBC * XDN;

        for (int kt = 0; kt < 512; kt += 64) {
            __syncthreads();
#pragma unroll
            for (int i = 0; i < 4; i++) {
                gload_lds16(Ap0 + i * (8 * 512) + kt, &As[0][(rbA + 8 * i) * 64]);
                gload_lds16(Ap1 + i * (8 * 512) + kt, &As[1][(rbA + 8 * i) * 64]);
            }
            gload_lds16(Bbase0 + (size_t)br0 * 128 + kt, &Bs[0][(rbB + 0) * 64]);
            gload_lds16(Bbase0 + (size_t)br1 * 128 + kt, &Bs[0][(rbB + 8) * 64]);
            gload_lds16(Bbase1 + (size_t)br0 * 128 + kt, &Bs[1][(rbB + 0) * 64]);
            gload_lds16(Bbase1 + (size_t)br1 * 128 + kt, &Bs[1][(rbB + 8) * 64]);
            __syncthreads();
#pragma unroll
            for (int rr2 = 0; rr2 < 2; rr2++) {
#pragma unroll
                for (int kk = 0; kk < 64; kk += 32) {
                    const int p = ((kk >> 5) * 4 + quad) ^ r7;
                    bf16x8 af[4], bfr[2];
#pragma unroll
                    for (int i = 0; i < 4; i++)
                        af[i] = *(const bf16x8*)(&As[rr2][(wm + i * 16 + l16) * 64 + p * 8]);
#pragma unroll
                    for (int j = 0; j < 2; j++)
                        bfr[j] = *(const bf16x8*)(&Bs[rr2][(wn + j * 16 + l16) * 64 + p * 8]);
#pragma unroll
                    for (int i = 0; i < 4; i++)
#pragma unroll
                        for (int j = 0; j < 2; j++)
                            acc[2 * rp + rr2][i][j] = __builtin_amdgcn_mfma_f32_16x16x32_bf16(
                                af[i], bfr[j], acc[2 * rp + rr2][i][j], 0, 0, 0);
                }
            }
        }
    }

    float* oRe = out + (size_t)bcg * KF * TT;
    float* oIm = out + (size_t)IMOFF + (size_t)bcg * KF * TT;

#pragma unroll
    for (int j = 0; j < 2; j++) {
        const int t = t0 + wn + j * 16 + l16;
        if (t >= TT) continue;
#pragma unroll
        for (int i = 0; i < 4; i++) {
            const int rowb = mBase + wm + i * 16 + quad * 4;
#pragma unroll
            for (int h = 0; h < 2; h++) {
                const int kap = (rowb >> 1) + h;
                const float u0 = acc[0][i][j][2 * h], v0 = acc[0][i][j][2 * h + 1];
                const float u1 = acc[1][i][j][2 * h], v1 = acc[1][i][j][2 * h + 1];
                const float u2 = acc[2][i][j][2 * h], v2 = acc[2][i][j][2 * h + 1];
                const float u3 = acc[3][i][j][2 * h], v3 = acc[3][i][j][2 * h + 1];
                const float Eu = u0 + u2, Epu = u0 - u2;
                const float Ou = u1 + u3, Opu = u1 - u3;
                const float Ev = v0 + v2, Epv = v0 - v2;
                const float Ov = v1 + v3, Opv = v1 - v3;
                const size_t rA = (size_t)kap * TT + t;
                const size_t rB = (size_t)(kap + 512) * TT + t;
                const size_t rC = (size_t)(512 - kap) * TT + t;
                const size_t rD = (size_t)(1024 - kap) * TT + t;
                oRe[rA] = Eu + Ou;    oIm[rA] = Ev + Ov;
                oRe[rB] = Epu + Opv;  oIm[rB] = Epv - Opu;
                oRe[rC] = Epu - Opv;  oIm[rC] = -(Epv + Opu);
                oRe[rD] = Eu - Ou;    oIm[rD] = -(Ev - Ov);
            }
        }
    }
}

// ---- tail: k in {256,768} re/im, t in [0,513)  (t=512 via clamped frame row)
__global__ __launch_bounds__(256)
void stft_tail(const float* __restrict__ wr, const float* __restrict__ wi,
               const short* __restrict__ xpad, float* __restrict__ out) {
    const int tb  = blockIdx.x;          // 0..8
    const int bc  = blockIdx.y;          // 0..31
    const int tid = threadIdx.x;
    const int lane = tid & 63;
    const int wid  = tid >> 6;
    const int l16  = lane & 15;
    const int quad = lane >> 4;

    const int t0 = (tb * 4 + wid) * 16;  // 0..560
    const int ls = l16 & 3;
    const int k  = 256 + (ls & 1) * 512;
    const float* bp = ((ls & 2) ? wi : wr) + (size_t)k * NFFT + quad * 8;
    const int tr = min(t0 + l16, 512);
    const short* ap = xpad + (size_t)bc * XPADN + (size_t)tr * HOPS + quad * 8;
    f32x4 acc0 = {0.f, 0.f, 0.f, 0.f}, acc1 = {0.f, 0.f, 0.f, 0.f};
    for (int kt = 0; kt < NFFT; kt += 64) {
        bf16x8 a0 = *(const bf16x8*)(ap + kt);
        bf16x8 a1 = *(const bf16x8*)(ap + kt + 32);
        float4 f0 = *(const float4*)(bp + kt), f1 = *(const float4*)(bp + kt + 4);
        float4 g0 = *(const float4*)(bp + kt + 32), g1 = *(const float4*)(bp + kt + 36);
        bf16x8 b0 = { f2bf(f0.x), f2bf(f0.y), f2bf(f0.z), f2bf(f0.w),
                      f2bf(f1.x), f2bf(f1.y), f2bf(f1.z), f2bf(f1.w) };
        bf16x8 b1 = { f2bf(g0.x), f2bf(g0.y), f2bf(g0.z), f2bf(g0.w),
                      f2bf(g1.x), f2bf(g1.y), f2bf(g1.z), f2bf(g1.w) };
        acc0 = __builtin_amdgcn_mfma_f32_16x16x32_bf16(a0, b0, acc0, 0, 0, 0);
        acc1 = __builtin_amdgcn_mfma_f32_16x16x32_bf16(a1, b1, acc1, 0, 0, 0);
    }
    if (l16 < 4) {
        size_t base = ((ls & 2) ? (size_t)IMOFF : 0) + (size_t)(bc * KF + k) * TT;
#pragma unroll
        for (int rr = 0; rr < 4; rr++) {
            int t = t0 + quad * 4 + rr;
            if (t < TT) out[base + t] = acc0[rr] + acc1[rr];
        }
    }
}

extern "C" void kernel_launch(void* const* d_in, const int* in_sizes, int n_in,
                              void* d_out, int out_size, void* d_ws, size_t ws_size,
                              hipStream_t stream) {
    const float* x  = (const float*)d_in[0];
    const float* wr = (const float*)d_in[1];
    const float* wi = (const float*)d_in[2];
    float* out = (float*)d_out;

    char* ws = (char*)d_ws;
    short* xpad = (short*)ws;                                  // 16,908,288 B
    short* xd   = (short*)(ws + 16908288);                     // 16,908,288 B
    short* Ab   = (short*)(ws + 33816576);                     //  2,097,152 B

    prep_x<<<dim3(258, NBC), 256, 0, stream>>>(x, xpad, xd);
    prep_basis2<<<dim3(512, 4), 256, 0, stream>>>(wr, wi, Ab);
    stft_gemm_f<<<dim3(NBC, 4, 9), 256, 0, stream>>>(Ab, xd, out);
    stft_tail<<<dim3(9, NBC), 256, 0, stream>>>(wr, wi, xpad, out);
}

// Round 3
// 279.636 us; speedup vs baseline: 1.1486x; 1.1281x over previous
//
#include <hip/hip_runtime.h>

#define NFFT  2048
#define KF    1025
#define MROWS 2050
#define TT    513
#define HOPS  512
#define LSIG  262144
#define PADL  1024
#define XPADN 264192              // LSIG + 2*PADL
#define XDN   66048               // XPADN / 4 (deinterleaved plane length)
#define IMOFF (16 * MROWS * TT)
#define NBC   32

typedef __attribute__((ext_vector_type(8))) short bf16x8;
typedef __attribute__((ext_vector_type(4))) short bf16x4;
typedef __attribute__((ext_vector_type(4))) float f32x4;

__device__ __forceinline__ short f2bf(float f) {
    union { float f; unsigned u; } v; v.f = f;
    unsigned r = v.u + 0x7fffu + ((v.u >> 16) & 1u);
    return (short)(r >> 16);
}

typedef __attribute__((address_space(1))) void gas_void;
typedef __attribute__((address_space(3))) void las_void;

__device__ __forceinline__ void gload_lds16(const short* g, short* l) {
    __builtin_amdgcn_global_load_lds((gas_void*)(void*)const_cast<short*>(g),
                                     (las_void*)(void*)l, 16, 0, 0);
}

// ---- prep: reflect-padded x -> bf16 xpad[32][264192] AND deinterleaved xd[4][32][66048]
__global__ __launch_bounds__(256)
void prep_x(const float* __restrict__ x, short* __restrict__ xpad,
            short* __restrict__ xd) {
    const int bc = blockIdx.y;
    const int j4 = (blockIdx.x * 256 + threadIdx.x) * 4;   // 258*256*4 = 264192 exact
    const float* xb = x + (size_t)bc * LSIG;
    float4 v;
    if (j4 >= PADL && j4 + 4 <= PADL + LSIG) {
        v = *(const float4*)(xb + (j4 - PADL));
    } else {
        float t[4];
#pragma unroll
        for (int e = 0; e < 4; e++) {
            int s = j4 + e - PADL;
            if (s < 0) s = -s;
            if (s >= LSIG) s = 2 * LSIG - 2 - s;
            t[e] = xb[s];
        }
        v = make_float4(t[0], t[1], t[2], t[3]);
    }
    bf16x4 b = { f2bf(v.x), f2bf(v.y), f2bf(v.z), f2bf(v.w) };
    *(bf16x4*)(xpad + (size_t)bc * XPADN + j4) = b;
    const int j = j4 >> 2;                                 // n = 4j + r
#pragma unroll
    for (int r = 0; r < 4; r++)
        xd[((size_t)r * NBC + bc) * XDN + j] = b[r];
}

// ---- prep: twiddle-baked radix-4 basis.
// A'[r][row=2kap+reim][m] = (reim ? wi : wr)[kap][4m+r]  (pure gather, no trig)
__global__ __launch_bounds__(256)
void prep_basis2(const float* __restrict__ wr, const float* __restrict__ wi,
                 short* __restrict__ A) {
    const int r   = blockIdx.y;
    const int row = blockIdx.x;               // 0..511, kap = row>>1
    const float* w = ((row & 1) ? wi : wr) + (size_t)(row >> 1) * NFFT + r;
    short* dst = A + ((size_t)r * 512 + row) * 512;
    for (int m = threadIdx.x; m < 512; m += 256)
        dst[m] = f2bf(w[4 * m]);
}

// ---- fused radix-4 GEMM + combine epilogue.
// Block: 128 basis rows (64 kaps) x 64 t; 8 waves (2M x 4T), wave = 64 rows x 16 t.
// acc[r][i]: 4 r-planes x 4 row-frags = 64 VGPR acc/thread -> 2 blocks/CU resident.
// blockIdx.z == 8 covers only t=512 (guarded stores; B rows clamped in-plane).
__global__ __launch_bounds__(512, 4)
void stft_gemm_f(const short* __restrict__ Ab, const short* __restrict__ xd,
                 float* __restrict__ out) {
    __shared__ short As[2][128 * 64];
    __shared__ short Bs[2][64 * 64];

    const int tid   = threadIdx.x;
    const int bcg   = blockIdx.x;
    const int mBase = blockIdx.y * 128;
    const int t0    = blockIdx.z * 64;

    const int lane = tid & 63;
    const int wid  = tid >> 6;                 // 0..7
    const int wm   = (wid >> 2) * 64;          // 2 M-groups of 64 rows
    const int wn   = (wid & 3) * 16;           // 4 T-groups of 16 t
    const int l16  = lane & 15;
    const int quad = lane >> 4;

    const int lrow = lane >> 3;
    const int csrc = (lane & 7) ^ lrow;

    // staging assignments (per wave): A rows [16w,16w+16) both planes, B row-block [8w,8w+8)
    const int raw = 16 * wid;                  // A row base for this wave
    const int rbw = 8 * wid;                   // B row base for this wave
    int brw = t0 + rbw + lrow; if (brw > 515) brw = 515;   // clamp in-plane (t=512 block)

    f32x4 acc[4][4];
#pragma unroll
    for (int r = 0; r < 4; r++)
#pragma unroll
        for (int i = 0; i < 4; i++)
            acc[r][i] = (f32x4){0.f, 0.f, 0.f, 0.f};

    const int r7 = l16 & 7;

#pragma unroll
    for (int rp = 0; rp < 2; rp++) {
        const short* Ap0 = Ab + ((size_t)(2 * rp) * 512 + mBase + raw + lrow) * 512 + csrc * 8;
        const short* Ap1 = Ap0 + (size_t)512 * 512;
        const short* Bp0 = xd + ((size_t)(2 * rp) * NBC + bcg) * XDN
                              + (size_t)brw * 128 + csrc * 8;
        const short* Bp1 = Bp0 + (size_t)NBC * XDN;

        for (int kt = 0; kt < 512; kt += 64) {
            __syncthreads();
#pragma unroll
            for (int i = 0; i < 2; i++) {
                gload_lds16(Ap0 + i * (8 * 512) + kt, &As[0][(raw + 8 * i) * 64]);
                gload_lds16(Ap1 + i * (8 * 512) + kt, &As[1][(raw + 8 * i) * 64]);
            }
            gload_lds16(Bp0 + kt, &Bs[0][rbw * 64]);
            gload_lds16(Bp1 + kt, &Bs[1][rbw * 64]);
            __syncthreads();
#pragma unroll
            for (int rr2 = 0; rr2 < 2; rr2++) {
#pragma unroll
                for (int kk = 0; kk < 64; kk += 32) {
                    const int p = ((kk >> 5) * 4 + quad) ^ r7;
                    bf16x8 af[4], bfr;
#pragma unroll
                    for (int i = 0; i < 4; i++)
                        af[i] = *(const bf16x8*)(&As[rr2][(wm + i * 16 + l16) * 64 + p * 8]);
                    bfr = *(const bf16x8*)(&Bs[rr2][(wn + l16) * 64 + p * 8]);
#pragma unroll
                    for (int i = 0; i < 4; i++)
                        acc[2 * rp + rr2][i] = __builtin_amdgcn_mfma_f32_16x16x32_bf16(
                            af[i], bfr, acc[2 * rp + rr2][i], 0, 0, 0);
                }
            }
        }
    }

    float* oRe = out + (size_t)bcg * KF * TT;
    float* oIm = out + (size_t)IMOFF + (size_t)bcg * KF * TT;

    const int t = t0 + wn + l16;
    if (t < TT) {
#pragma unroll
        for (int i = 0; i < 4; i++) {
            const int rowb = mBase + wm + i * 16 + quad * 4;
#pragma unroll
            for (int h = 0; h < 2; h++) {
                const int kap = (rowb >> 1) + h;
                const float u0 = acc[0][i][2 * h], v0 = acc[0][i][2 * h + 1];
                const float u1 = acc[1][i][2 * h], v1 = acc[1][i][2 * h + 1];
                const float u2 = acc[2][i][2 * h], v2 = acc[2][i][2 * h + 1];
                const float u3 = acc[3][i][2 * h], v3 = acc[3][i][2 * h + 1];
                const float Eu = u0 + u2, Epu = u0 - u2;
                const float Ou = u1 + u3, Opu = u1 - u3;
                const float Ev = v0 + v2, Epv = v0 - v2;
                const float Ov = v1 + v3, Opv = v1 - v3;
                const size_t rA = (size_t)kap * TT + t;
                const size_t rB = (size_t)(kap + 512) * TT + t;
                const size_t rC = (size_t)(512 - kap) * TT + t;
                const size_t rD = (size_t)(1024 - kap) * TT + t;
                oRe[rA] = Eu + Ou;    oIm[rA] = Ev + Ov;
                oRe[rB] = Epu + Opv;  oIm[rB] = Epv - Opu;
                oRe[rC] = Epu - Opv;  oIm[rC] = -(Epv + Opu);
                oRe[rD] = Eu - Ou;    oIm[rD] = -(Ev - Ov);
            }
        }
    }
}

// ---- tail: k in {256,768} re/im, t in [0,513)  (t=512 via clamped frame row)
__global__ __launch_bounds__(256)
void stft_tail(const float* __restrict__ wr, const float* __restrict__ wi,
               const short* __restrict__ xpad, float* __restrict__ out) {
    const int tb  = blockIdx.x;          // 0..8
    const int bc  = blockIdx.y;          // 0..31
    const int tid = threadIdx.x;
    const int lane = tid & 63;
    const int wid  = tid >> 6;
    const int l16  = lane & 15;
    const int quad = lane >> 4;

    const int t0 = (tb * 4 + wid) * 16;  // 0..560
    const int ls = l16 & 3;
    const int k  = 256 + (ls & 1) * 512;
    const float* bp = ((ls & 2) ? wi : wr) + (size_t)k * NFFT + quad * 8;
    const int tr = min(t0 + l16, 512);
    const short* ap = xpad + (size_t)bc * XPADN + (size_t)tr * HOPS + quad * 8;
    f32x4 acc0 = {0.f, 0.f, 0.f, 0.f}, acc1 = {0.f, 0.f, 0.f, 0.f};
    for (int kt = 0; kt < NFFT; kt += 64) {
        bf16x8 a0 = *(const bf16x8*)(ap + kt);
        bf16x8 a1 = *(const bf16x8*)(ap + kt + 32);
        float4 f0 = *(const float4*)(bp + kt), f1 = *(const float4*)(bp + kt + 4);
        float4 g0 = *(const float4*)(bp + kt + 32), g1 = *(const float4*)(bp + kt + 36);
        bf16x8 b0 = { f2bf(f0.x), f2bf(f0.y), f2bf(f0.z), f2bf(f0.w),
                      f2bf(f1.x), f2bf(f1.y), f2bf(f1.z), f2bf(f1.w) };
        bf16x8 b1 = { f2bf(g0.x), f2bf(g0.y), f2bf(g0.z), f2bf(g0.w),
                      f2bf(g1.x), f2bf(g1.y), f2bf(g1.z), f2bf(g1.w) };
        acc0 = __builtin_amdgcn_mfma_f32_16x16x32_bf16(a0, b0, acc0, 0, 0, 0);
        acc1 = __builtin_amdgcn_mfma_f32_16x16x32_bf16(a1, b1, acc1, 0, 0, 0);
    }
    if (l16 < 4) {
        size_t base = ((ls & 2) ? (size_t)IMOFF : 0) + (size_t)(bc * KF + k) * TT;
#pragma unroll
        for (int rr = 0; rr < 4; rr++) {
            int t = t0 + quad * 4 + rr;
            if (t < TT) out[base + t] = acc0[rr] + acc1[rr];
        }
    }
}

extern "C" void kernel_launch(void* const* d_in, const int* in_sizes, int n_in,
                              void* d_out, int out_size, void* d_ws, size_t ws_size,
                              hipStream_t stream) {
    const float* x  = (const float*)d_in[0];
    const float* wr = (const float*)d_in[1];
    const float* wi = (const float*)d_in[2];
    float* out = (float*)d_out;

    char* ws = (char*)d_ws;
    short* xpad = (short*)ws;                                  // 16,908,288 B
    short* xd   = (short*)(ws + 16908288);                     // 16,908,288 B
    short* Ab   = (short*)(ws + 33816576);                     //  2,097,152 B

    prep_x<<<dim3(258, NBC), 256, 0, stream>>>(x, xpad, xd);
    prep_basis2<<<dim3(512, 4), 256, 0, stream>>>(wr, wi, Ab);
    stft_gemm_f<<<dim3(NBC, 4, 9), 512, 0, stream>>>(Ab, xd, out);
    stft_tail<<<dim3(9, NBC), 256, 0, stream>>>(wr, wi, xpad, out);
}